// Round 1
// baseline (653.055 us; speedup 1.0000x reference)
//
#include <hip/hip_runtime.h>
#include <math.h>

#define NN 100000
#define NE 1600000
#define NT (NE + NN)   // 1700000 edges incl. self-loops
#define DD 128

// ---------------- preprocessing kernels ----------------

__global__ __launch_bounds__(256) void k_init(int* __restrict__ deg, int* __restrict__ fill){
  int i = blockIdx.x*256 + threadIdx.x;
  if (i < NN){ deg[i] = 1; fill[i] = 0; }   // deg starts at 1: the self-loop
}

__global__ __launch_bounds__(256) void k_count(const int* __restrict__ dst, int* __restrict__ deg){
  int i = blockIdx.x*256 + threadIdx.x;
  if (i < NE) atomicAdd(&deg[dst[i]], 1);
}

__global__ __launch_bounds__(256) void k_dis(const int* __restrict__ deg, float* __restrict__ dis){
  int i = blockIdx.x*256 + threadIdx.x;
  if (i < NN) dis[i] = rsqrtf((float)deg[i]);   // deg >= 1 always
}

// exclusive scan of deg -> rowptr, three passes
__global__ __launch_bounds__(256) void k_scanA(const int* __restrict__ deg, int* __restrict__ rowptr,
                                               int* __restrict__ bsum){
  __shared__ int s[256];
  int t = threadIdx.x; int i = blockIdx.x*256 + t;
  int v = (i < NN) ? deg[i] : 0;
  s[t] = v;
  __syncthreads();
  for (int off = 1; off < 256; off <<= 1){
    int a = (t >= off) ? s[t-off] : 0;
    __syncthreads();
    s[t] += a;
    __syncthreads();
  }
  if (i < NN) rowptr[i] = s[t] - v;         // block-local exclusive
  if (t == 255) bsum[blockIdx.x] = s[255];  // block total
}

__global__ __launch_bounds__(512) void k_scanB(int* __restrict__ bsum, int nb){
  __shared__ int s[512];
  int t = threadIdx.x;
  int v = (t < nb) ? bsum[t] : 0;
  s[t] = v;
  __syncthreads();
  for (int off = 1; off < 512; off <<= 1){
    int a = (t >= off) ? s[t-off] : 0;
    __syncthreads();
    s[t] += a;
    __syncthreads();
  }
  if (t < nb) bsum[t] = s[t] - v;           // exclusive block offsets
}

__global__ __launch_bounds__(256) void k_scanC(int* __restrict__ rowptr, const int* __restrict__ bsum){
  int i = blockIdx.x*256 + threadIdx.x;
  if (i < NN) rowptr[i] += bsum[blockIdx.x];
  if (i == 0) rowptr[NN] = NT;
}

// counting-sort edges by dst into CSR; also precompute norm per edge
__global__ __launch_bounds__(256) void k_scatter(const int* __restrict__ ei, const float* __restrict__ dis,
    const int* __restrict__ rowptr, int* __restrict__ fill,
    int* __restrict__ es_src, float* __restrict__ es_norm){
  int i = blockIdx.x*256 + threadIdx.x;
  if (i < NE){
    int s = ei[i];           // src row
    int d = ei[NE + i];      // dst row
    int p = rowptr[d] + atomicAdd(&fill[d], 1);
    es_src[p] = s;
    es_norm[p] = dis[s] * dis[d];
  } else if (i < NT){
    int n = i - NE;          // self-loop
    int p = rowptr[n] + atomicAdd(&fill[n], 1);
    es_src[p] = n;
    es_norm[p] = dis[n] * dis[n];
  }
}

// ---------------- fp32 GEMM: Y[nrows,128] = X[nrows,128] @ W[128,128] ----------------
// 128 rows/block, 256 threads, 8x8 register tile/thread.
// LDS: W k-half (32KB) + transposed X k-half (32KB) = 64KB -> 2 blocks/CU.
__global__ __launch_bounds__(256, 2) void k_gemm(const float* __restrict__ X, const float* __restrict__ W,
    float* __restrict__ Y, int nrows){
  __shared__ float Ws[64*128];
  __shared__ float Xt[64*128];   // [k_local][row], XOR-swizzled rows
  int t = threadIdx.x;
  int row0 = blockIdx.x * 128;
  int tc = t & 15, tr = t >> 4;
  float acc[8][8];
  #pragma unroll
  for (int i=0;i<8;i++)
    #pragma unroll
    for (int j=0;j<8;j++) acc[i][j]=0.f;

  for (int ph = 0; ph < 2; ++ph){
    int k0 = ph * 64;
    // stage W rows k0..k0+63 (linear, coalesced)
    #pragma unroll
    for (int it = 0; it < 8; ++it){
      int f = it*256 + t;                    // 0..2047 float4s
      ((float4*)Ws)[f] = ((const float4*)W)[k0*32 + f];
    }
    // stage X rows row0..row0+127, cols k0..k0+63, transposed with XOR swizzle
    #pragma unroll
    for (int it = 0; it < 8; ++it){
      int f = it*256 + t;                    // 0..2047
      int r  = f >> 4;                       // local row 0..127
      int c4 = f & 15;                       // float4 within k-half
      int gr = row0 + r;
      float4 v;
      if (gr < nrows) v = ((const float4*)X)[(size_t)gr*32 + (k0>>2) + c4];
      else            v = make_float4(0.f,0.f,0.f,0.f);
      int swz = (c4 & 3) << 3;               // == ((k>>2)&3)<<3 for k=4*c4+j
      int rp  = r ^ swz;
      Xt[(c4*4+0)*128 + rp] = v.x;
      Xt[(c4*4+1)*128 + rp] = v.y;
      Xt[(c4*4+2)*128 + rp] = v.z;
      Xt[(c4*4+3)*128 + rp] = v.w;
    }
    __syncthreads();
    #pragma unroll 4
    for (int kl = 0; kl < 64; ++kl){
      int swz = ((kl >> 2) & 3) << 3;
      int xb  = kl*128 + ((tr*8) ^ swz);     // swz has no bit 2 -> +4 stays consistent
      float4 xa = *(const float4*)&Xt[xb];
      float4 xc = *(const float4*)&Xt[xb + 4];
      float4 wa = *(const float4*)&Ws[kl*128 + tc*8];
      float4 wb = *(const float4*)&Ws[kl*128 + tc*8 + 4];
      float xr[8] = {xa.x,xa.y,xa.z,xa.w,xc.x,xc.y,xc.z,xc.w};
      float wr[8] = {wa.x,wa.y,wa.z,wa.w,wb.x,wb.y,wb.z,wb.w};
      #pragma unroll
      for (int i=0;i<8;i++)
        #pragma unroll
        for (int j=0;j<8;j++)
          acc[i][j] = fmaf(xr[i], wr[j], acc[i][j]);
    }
    __syncthreads();
  }
  #pragma unroll
  for (int i=0;i<8;i++){
    int r = row0 + tr*8 + i;
    if (r < nrows){
      float4 o0 = make_float4(acc[i][0],acc[i][1],acc[i][2],acc[i][3]);
      float4 o1 = make_float4(acc[i][4],acc[i][5],acc[i][6],acc[i][7]);
      ((float4*)Y)[(size_t)r*32 + tc*2 + 0] = o0;
      ((float4*)Y)[(size_t)r*32 + tc*2 + 1] = o1;
    }
  }
}

// ---------------- CSR aggregation + bias + ELU ----------------
// one node per 128-thread block; thread = channel; register accumulate, one write
__global__ __launch_bounds__(128) void k_agg(const float* __restrict__ H,
    const int* __restrict__ rowptr, const int* __restrict__ es_src,
    const float* __restrict__ es_norm, const float* __restrict__ bias,
    float* __restrict__ out){
  int n = blockIdx.x;
  int c = threadIdx.x;
  int e0 = rowptr[n], e1 = rowptr[n+1];
  float acc = 0.f;
  for (int e = e0; e < e1; ++e){
    int   s = es_src[e];     // uniform across block -> scalar load
    float w = es_norm[e];
    acc = fmaf(w, H[(size_t)s*DD + c], acc);
  }
  float v = acc + bias[c];
  out[(size_t)n*DD + c] = (v > 0.f) ? v : expm1f(v);
}

// ---------------- launch ----------------

extern "C" void kernel_launch(void* const* d_in, const int* in_sizes, int n_in,
                              void* d_out, int out_size, void* d_ws, size_t ws_size,
                              hipStream_t stream){
  const float* x  = (const float*)d_in[0];
  const int*   ei = (const int*)d_in[1];   // [2, NE]: src row then dst row
  const float* W1 = (const float*)d_in[2];
  const float* b1 = (const float*)d_in[3];
  const float* W2 = (const float*)d_in[4];
  const float* b2 = (const float*)d_in[5];
  float* out = (float*)d_out;

  // workspace carve-up (int-sized offsets; H kept 16B-aligned)
  int*   ws_i    = (int*)d_ws;
  int*   deg     = ws_i + 0;               // 100000
  int*   fill    = ws_i + 100000;          // 100000
  int*   rowptr  = ws_i + 200000;          // 100001
  int*   bsum    = ws_i + 300004;          // 512
  float* dis     = (float*)(ws_i + 300516);// 100000
  int*   es_src  = ws_i + 400516;          // 1700000
  float* es_norm = (float*)(ws_i + 2100516); // 1700000
  float* H       = (float*)(ws_i + 3800516); // 12800000  (~66.4MB total)

  // build normalized CSR (recomputed every call; no cached state)
  k_init   <<<391, 256, 0, stream>>>(deg, fill);
  k_count  <<<6250,256, 0, stream>>>(ei + NE, deg);
  k_dis    <<<391, 256, 0, stream>>>(deg, dis);
  k_scanA  <<<391, 256, 0, stream>>>(deg, rowptr, bsum);
  k_scanB  <<<1,   512, 0, stream>>>(bsum, 391);
  k_scanC  <<<391, 256, 0, stream>>>(rowptr, bsum);
  k_scatter<<<6641,256, 0, stream>>>(ei, dis, rowptr, fill, es_src, es_norm);

  // layer 1: H = x@W1 ; out = elu(agg(H) + b1)   (d_out doubles as activation buffer)
  k_gemm<<<782, 256, 0, stream>>>(x, W1, H, NN);
  k_agg <<<NN,  128, 0, stream>>>(H, rowptr, es_src, es_norm, b1, out);
  // layer 2: H = out@W2 ; out = elu(agg(H) + b2)
  k_gemm<<<782, 256, 0, stream>>>(out, W2, H, NN);
  k_agg <<<NN,  128, 0, stream>>>(H, rowptr, es_src, es_norm, b2, out);
}

// Round 2
// 551.329 us; speedup vs baseline: 1.1845x; 1.1845x over previous
//
#include <hip/hip_runtime.h>
#include <math.h>

#define NN 100000
#define NE 1600000
#define NT (NE + NN)   // 1700000 edges incl. self-loops
#define DD 128

// ---------------- preprocessing kernels ----------------

__global__ __launch_bounds__(256) void k_init(int* __restrict__ deg, int* __restrict__ fill){
  int i = blockIdx.x*256 + threadIdx.x;
  if (i < NN){ deg[i] = 1; fill[i] = 0; }   // deg starts at 1: the self-loop
}

__global__ __launch_bounds__(256) void k_count(const int* __restrict__ dst, int* __restrict__ deg){
  int i = blockIdx.x*256 + threadIdx.x;
  if (i < NE) atomicAdd(&deg[dst[i]], 1);
}

__global__ __launch_bounds__(256) void k_dis(const int* __restrict__ deg, float* __restrict__ dis){
  int i = blockIdx.x*256 + threadIdx.x;
  if (i < NN) dis[i] = rsqrtf((float)deg[i]);   // deg >= 1 always
}

// exclusive scan of deg -> rowptr, three passes
__global__ __launch_bounds__(256) void k_scanA(const int* __restrict__ deg, int* __restrict__ rowptr,
                                               int* __restrict__ bsum){
  __shared__ int s[256];
  int t = threadIdx.x; int i = blockIdx.x*256 + t;
  int v = (i < NN) ? deg[i] : 0;
  s[t] = v;
  __syncthreads();
  for (int off = 1; off < 256; off <<= 1){
    int a = (t >= off) ? s[t-off] : 0;
    __syncthreads();
    s[t] += a;
    __syncthreads();
  }
  if (i < NN) rowptr[i] = s[t] - v;         // block-local exclusive
  if (t == 255) bsum[blockIdx.x] = s[255];  // block total
}

__global__ __launch_bounds__(512) void k_scanB(int* __restrict__ bsum, int nb){
  __shared__ int s[512];
  int t = threadIdx.x;
  int v = (t < nb) ? bsum[t] : 0;
  s[t] = v;
  __syncthreads();
  for (int off = 1; off < 512; off <<= 1){
    int a = (t >= off) ? s[t-off] : 0;
    __syncthreads();
    s[t] += a;
    __syncthreads();
  }
  if (t < nb) bsum[t] = s[t] - v;           // exclusive block offsets
}

__global__ __launch_bounds__(256) void k_scanC(int* __restrict__ rowptr, const int* __restrict__ bsum){
  int i = blockIdx.x*256 + threadIdx.x;
  if (i < NN) rowptr[i] += bsum[blockIdx.x];
  if (i == 0) rowptr[NN] = NT;
}

// counting-sort edges by dst into CSR; packed (src, norm-bits) descriptor
__global__ __launch_bounds__(256) void k_scatter(const int* __restrict__ ei, const float* __restrict__ dis,
    const int* __restrict__ rowptr, int* __restrict__ fill,
    int2* __restrict__ es){
  int i = blockIdx.x*256 + threadIdx.x;
  if (i < NE){
    int s = ei[i];           // src row
    int d = ei[NE + i];      // dst row
    int p = rowptr[d] + atomicAdd(&fill[d], 1);
    es[p] = make_int2(s, __float_as_int(dis[s] * dis[d]));
  } else if (i < NT){
    int n = i - NE;          // self-loop
    int p = rowptr[n] + atomicAdd(&fill[n], 1);
    float dn = dis[n];
    es[p] = make_int2(n, __float_as_int(dn * dn));
  }
}

// ---------------- fp32 GEMM: Y[nrows,128] = X[nrows,128] @ W[128,128] ----------------
// 128 rows/block, 256 threads, 8x8 register tile/thread.
// LDS: W k-half (32KB) + transposed X k-half (32KB) = 64KB -> 2 blocks/CU.
__global__ __launch_bounds__(256, 2) void k_gemm(const float* __restrict__ X, const float* __restrict__ W,
    float* __restrict__ Y, int nrows){
  __shared__ float Ws[64*128];
  __shared__ float Xt[64*128];   // [k_local][row], XOR-swizzled rows
  int t = threadIdx.x;
  int row0 = blockIdx.x * 128;
  int tc = t & 15, tr = t >> 4;
  float acc[8][8];
  #pragma unroll
  for (int i=0;i<8;i++)
    #pragma unroll
    for (int j=0;j<8;j++) acc[i][j]=0.f;

  for (int ph = 0; ph < 2; ++ph){
    int k0 = ph * 64;
    // stage W rows k0..k0+63 (linear, coalesced)
    #pragma unroll
    for (int it = 0; it < 8; ++it){
      int f = it*256 + t;                    // 0..2047 float4s
      ((float4*)Ws)[f] = ((const float4*)W)[k0*32 + f];
    }
    // stage X rows row0..row0+127, cols k0..k0+63, transposed with XOR swizzle
    #pragma unroll
    for (int it = 0; it < 8; ++it){
      int f = it*256 + t;                    // 0..2047
      int r  = f >> 4;                       // local row 0..127
      int c4 = f & 15;                       // float4 within k-half
      int gr = row0 + r;
      float4 v;
      if (gr < nrows) v = ((const float4*)X)[(size_t)gr*32 + (k0>>2) + c4];
      else            v = make_float4(0.f,0.f,0.f,0.f);
      int swz = (c4 & 3) << 3;               // == ((k>>2)&3)<<3 for k=4*c4+j
      int rp  = r ^ swz;
      Xt[(c4*4+0)*128 + rp] = v.x;
      Xt[(c4*4+1)*128 + rp] = v.y;
      Xt[(c4*4+2)*128 + rp] = v.z;
      Xt[(c4*4+3)*128 + rp] = v.w;
    }
    __syncthreads();
    #pragma unroll 4
    for (int kl = 0; kl < 64; ++kl){
      int swz = ((kl >> 2) & 3) << 3;
      int xb  = kl*128 + ((tr*8) ^ swz);     // swz has no bit 2 -> +4 stays consistent
      float4 xa = *(const float4*)&Xt[xb];
      float4 xc = *(const float4*)&Xt[xb + 4];
      float4 wa = *(const float4*)&Ws[kl*128 + tc*8];
      float4 wb = *(const float4*)&Ws[kl*128 + tc*8 + 4];
      float xr[8] = {xa.x,xa.y,xa.z,xa.w,xc.x,xc.y,xc.z,xc.w};
      float wr[8] = {wa.x,wa.y,wa.z,wa.w,wb.x,wb.y,wb.z,wb.w};
      #pragma unroll
      for (int i=0;i<8;i++)
        #pragma unroll
        for (int j=0;j<8;j++)
          acc[i][j] = fmaf(xr[i], wr[j], acc[i][j]);
    }
    __syncthreads();
  }
  #pragma unroll
  for (int i=0;i<8;i++){
    int r = row0 + tr*8 + i;
    if (r < nrows){
      float4 o0 = make_float4(acc[i][0],acc[i][1],acc[i][2],acc[i][3]);
      float4 o1 = make_float4(acc[i][4],acc[i][5],acc[i][6],acc[i][7]);
      ((float4*)Y)[(size_t)r*32 + tc*2 + 0] = o0;
      ((float4*)Y)[(size_t)r*32 + tc*2 + 1] = o1;
    }
  }
}

// ---------------- CSR aggregation + bias + ELU ----------------
// one WAVE per node (4 nodes / 256-thread block); lane = channel pair (float2);
// 8x edge unroll -> 8 gathers in flight per wave.
__global__ __launch_bounds__(256) void k_agg(const float* __restrict__ H,
    const int* __restrict__ rowptr, const int2* __restrict__ es,
    const float* __restrict__ bias, float* __restrict__ out){
  int wid  = threadIdx.x >> 6;
  int lane = threadIdx.x & 63;
  int n = blockIdx.x*4 + wid;            // grid*4 == NN exactly
  int e0 = rowptr[n], e1 = rowptr[n+1];
  float a0 = 0.f, a1 = 0.f;
  int e = e0;

#define ASTEP(k) { int2 p##k = es[e+k]; \
    float2 h##k = *(const float2*)&H[(size_t)p##k.x*DD + lane*2]; \
    float  w##k = __int_as_float(p##k.y); \
    a0 = fmaf(w##k, h##k.x, a0); a1 = fmaf(w##k, h##k.y, a1); }

  for (; e + 8 <= e1; e += 8){
    ASTEP(0) ASTEP(1) ASTEP(2) ASTEP(3) ASTEP(4) ASTEP(5) ASTEP(6) ASTEP(7)
  }
  for (; e + 2 <= e1; e += 2){
    ASTEP(0) ASTEP(1)
  }
  if (e < e1){ ASTEP(0) }
#undef ASTEP

  float2 b = *(const float2*)&bias[lane*2];
  float v0 = a0 + b.x, v1 = a1 + b.y;
  float2 o;
  o.x = (v0 > 0.f) ? v0 : expm1f(v0);
  o.y = (v1 > 0.f) ? v1 : expm1f(v1);
  *(float2*)&out[(size_t)n*DD + lane*2] = o;
}

// ---------------- launch ----------------

extern "C" void kernel_launch(void* const* d_in, const int* in_sizes, int n_in,
                              void* d_out, int out_size, void* d_ws, size_t ws_size,
                              hipStream_t stream){
  const float* x  = (const float*)d_in[0];
  const int*   ei = (const int*)d_in[1];   // [2, NE]: src row then dst row
  const float* W1 = (const float*)d_in[2];
  const float* b1 = (const float*)d_in[3];
  const float* W2 = (const float*)d_in[4];
  const float* b2 = (const float*)d_in[5];
  float* out = (float*)d_out;

  // workspace carve-up (int-sized offsets; es 8B-aligned, H 16B-aligned)
  int*   ws_i    = (int*)d_ws;
  int*   deg     = ws_i + 0;                 // 100000
  int*   fill    = ws_i + 100000;            // 100000
  int*   rowptr  = ws_i + 200000;            // 100001
  int*   bsum    = ws_i + 300004;            // 512
  float* dis     = (float*)(ws_i + 300516);  // 100000
  int2*  es      = (int2*)(ws_i + 400516);   // 1700000 int2 (byte off 1602064, 8B-aligned)
  float* H       = (float*)(ws_i + 3800516); // 12800000 floats (byte off 15202064, 16B-aligned)

  // build normalized CSR (recomputed every call; no cached state)
  k_init   <<<391, 256, 0, stream>>>(deg, fill);
  k_count  <<<6250,256, 0, stream>>>(ei + NE, deg);
  k_dis    <<<391, 256, 0, stream>>>(deg, dis);
  k_scanA  <<<391, 256, 0, stream>>>(deg, rowptr, bsum);
  k_scanB  <<<1,   512, 0, stream>>>(bsum, 391);
  k_scanC  <<<391, 256, 0, stream>>>(rowptr, bsum);
  k_scatter<<<6641,256, 0, stream>>>(ei, dis, rowptr, fill, es);

  // layer 1: H = x@W1 ; out = elu(agg(H) + b1)   (d_out doubles as activation buffer)
  k_gemm<<<782,   256, 0, stream>>>(x, W1, H, NN);
  k_agg <<<25000, 256, 0, stream>>>(H, rowptr, es, b1, out);
  // layer 2: H = out@W2 ; out = elu(agg(H) + b2)
  k_gemm<<<782,   256, 0, stream>>>(out, W2, H, NN);
  k_agg <<<25000, 256, 0, stream>>>(H, rowptr, es, b2, out);
}

// Round 3
// 438.011 us; speedup vs baseline: 1.4910x; 1.2587x over previous
//
#include <hip/hip_runtime.h>
#include <math.h>

#define NN 100000
#define NE 1600000
#define NT (NE + NN)   // 1700000 edges incl. self-loops
#define DD 128

typedef unsigned int uint;

// round-to-nearest-even fp32 -> bf16 (as 16-bit payload in a uint)
__device__ __forceinline__ uint bfr(float f){
  uint u = __float_as_uint(f);
  return (u + 0x7FFFu + ((u >> 16) & 1u)) >> 16;
}
__device__ __forceinline__ uint pk2(float a, float b){
  return (bfr(a) & 0xFFFFu) | (bfr(b) << 16);
}

// ---------------- preprocessing ----------------

// deg[] zeroed by memset; counts in-edges only (self-loop folded in later as +1)
__global__ __launch_bounds__(256) void k_count(const int* __restrict__ dst, int* __restrict__ deg){
  int i = blockIdx.x*256 + threadIdx.x;
  if (i < NE) atomicAdd(&deg[dst[i]], 1);
}

// fused exclusive scan (block scan + global atomic base) + dis = rsqrt(deg+1)
__global__ __launch_bounds__(256) void k_scan(const int* __restrict__ deg, int* __restrict__ rowptr,
                                              int* __restrict__ gcnt, float* __restrict__ dis){
  __shared__ int s[256];
  __shared__ int base;
  int t = threadIdx.x, i = blockIdx.x*256 + t;
  int v = (i < NN) ? (deg[i] + 1) : 0;
  s[t] = v;
  __syncthreads();
  for (int off = 1; off < 256; off <<= 1){
    int a = (t >= off) ? s[t-off] : 0;
    __syncthreads();
    s[t] += a;
    __syncthreads();
  }
  if (t == 255) base = atomicAdd(gcnt, s[255]);
  __syncthreads();
  if (i < NN){
    rowptr[i] = base + s[t] - v;        // exclusive offset for node i
    dis[i] = rsqrtf((float)(deg[i] + 1));
  }
}

// counting-sort edges by dst; descriptor = src(17b) | norm-bf16-sans-sign(15b)<<17
__global__ __launch_bounds__(256) void k_scatter(const int* __restrict__ ei, const float* __restrict__ dis,
    const int* __restrict__ rowptr, int* __restrict__ fill, uint* __restrict__ es){
  int i = blockIdx.x*256 + threadIdx.x;
  if (i < NE){
    int s = ei[i];           // src row
    int d = ei[NE + i];      // dst row
    int p = rowptr[d] + atomicAdd(&fill[d], 1);
    es[p] = (uint)s | ((bfr(dis[s] * dis[d]) & 0x7FFFu) << 17);
  } else if (i < NT){
    int n = i - NE;          // self-loop
    int p = rowptr[n] + atomicAdd(&fill[n], 1);
    float dn = dis[n];
    es[p] = (uint)n | ((bfr(dn * dn) & 0x7FFFu) << 17);
  }
}

// ---------------- fp32 GEMM -> bf16 out: Y[nrows,128](bf16) = X[nrows,128] @ W[128,128] ----------------
// 128 rows/block, 256 threads, 8x8 register tile/thread.
// LDS: W k-half (32KB) + transposed X k-half (32KB) = 64KB -> 2 blocks/CU.
__global__ __launch_bounds__(256, 2) void k_gemm(const float* __restrict__ X, const float* __restrict__ W,
    uint* __restrict__ Y, int nrows){
  __shared__ float Ws[64*128];
  __shared__ float Xt[64*128];   // [k_local][row], XOR-swizzled rows
  int t = threadIdx.x;
  int row0 = blockIdx.x * 128;
  int tc = t & 15, tr = t >> 4;
  float acc[8][8];
  #pragma unroll
  for (int i=0;i<8;i++)
    #pragma unroll
    for (int j=0;j<8;j++) acc[i][j]=0.f;

  for (int ph = 0; ph < 2; ++ph){
    int k0 = ph * 64;
    #pragma unroll
    for (int it = 0; it < 8; ++it){
      int f = it*256 + t;                    // 0..2047 float4s
      ((float4*)Ws)[f] = ((const float4*)W)[k0*32 + f];
    }
    #pragma unroll
    for (int it = 0; it < 8; ++it){
      int f = it*256 + t;                    // 0..2047
      int r  = f >> 4;                       // local row 0..127
      int c4 = f & 15;                       // float4 within k-half
      int gr = row0 + r;
      float4 v;
      if (gr < nrows) v = ((const float4*)X)[(size_t)gr*32 + (k0>>2) + c4];
      else            v = make_float4(0.f,0.f,0.f,0.f);
      int swz = (c4 & 3) << 3;               // == ((k>>2)&3)<<3 for k=4*c4+j
      int rp  = r ^ swz;
      Xt[(c4*4+0)*128 + rp] = v.x;
      Xt[(c4*4+1)*128 + rp] = v.y;
      Xt[(c4*4+2)*128 + rp] = v.z;
      Xt[(c4*4+3)*128 + rp] = v.w;
    }
    __syncthreads();
    #pragma unroll 4
    for (int kl = 0; kl < 64; ++kl){
      int swz = ((kl >> 2) & 3) << 3;
      int xb  = kl*128 + ((tr*8) ^ swz);     // swz has no bit 2 -> +4 stays consistent
      float4 xa = *(const float4*)&Xt[xb];
      float4 xc = *(const float4*)&Xt[xb + 4];
      float4 wa = *(const float4*)&Ws[kl*128 + tc*8];
      float4 wb = *(const float4*)&Ws[kl*128 + tc*8 + 4];
      float xr[8] = {xa.x,xa.y,xa.z,xa.w,xc.x,xc.y,xc.z,xc.w};
      float wr[8] = {wa.x,wa.y,wa.z,wa.w,wb.x,wb.y,wb.z,wb.w};
      #pragma unroll
      for (int i=0;i<8;i++)
        #pragma unroll
        for (int j=0;j<8;j++)
          acc[i][j] = fmaf(xr[i], wr[j], acc[i][j]);
    }
    __syncthreads();
  }
  #pragma unroll
  for (int i=0;i<8;i++){
    int r = row0 + tr*8 + i;
    if (r < nrows){
      uint4 o;
      o.x = pk2(acc[i][0], acc[i][1]);
      o.y = pk2(acc[i][2], acc[i][3]);
      o.z = pk2(acc[i][4], acc[i][5]);
      o.w = pk2(acc[i][6], acc[i][7]);
      ((uint4*)Y)[(size_t)r*16 + tc] = o;   // 64 uints (128 bf16) per row
    }
  }
}

// ---------------- CSR aggregation + bias + ELU ----------------
// one WAVE per node (4 nodes / 256-thread block); lane = bf16 channel pair;
// 8x edge unroll -> 8 gathers in flight per wave.
__global__ __launch_bounds__(256) void k_agg(const uint* __restrict__ H,
    const int* __restrict__ rowptr, const int* __restrict__ deg,
    const uint* __restrict__ es, const float* __restrict__ bias,
    float* __restrict__ out){
  int wid  = threadIdx.x >> 6;
  int lane = threadIdx.x & 63;
  int n = blockIdx.x*4 + wid;            // grid*4 == NN exactly
  int e0 = rowptr[n];
  int e1 = e0 + deg[n] + 1;
  float a0 = 0.f, a1 = 0.f;
  int e = e0;

#define ASTEP(k) { uint p##k = es[e+k]; \
    uint h##k = H[(size_t)(p##k & 0x1FFFFu)*64 + lane]; \
    float w##k = __uint_as_float((p##k >> 17) << 16); \
    a0 = fmaf(w##k, __uint_as_float(h##k << 16), a0); \
    a1 = fmaf(w##k, __uint_as_float(h##k & 0xFFFF0000u), a1); }

  for (; e + 8 <= e1; e += 8){
    ASTEP(0) ASTEP(1) ASTEP(2) ASTEP(3) ASTEP(4) ASTEP(5) ASTEP(6) ASTEP(7)
  }
  for (; e + 2 <= e1; e += 2){
    ASTEP(0) ASTEP(1)
  }
  if (e < e1){ ASTEP(0) }
#undef ASTEP

  float2 b = *(const float2*)&bias[lane*2];
  float v0 = a0 + b.x, v1 = a1 + b.y;
  float2 o;
  o.x = (v0 > 0.f) ? v0 : expm1f(v0);
  o.y = (v1 > 0.f) ? v1 : expm1f(v1);
  *(float2*)&out[(size_t)n*DD + lane*2] = o;
}

// ---------------- launch ----------------

extern "C" void kernel_launch(void* const* d_in, const int* in_sizes, int n_in,
                              void* d_out, int out_size, void* d_ws, size_t ws_size,
                              hipStream_t stream){
  const float* x  = (const float*)d_in[0];
  const int*   ei = (const int*)d_in[1];   // [2, NE]: src row then dst row
  const float* W1 = (const float*)d_in[2];
  const float* b1 = (const float*)d_in[3];
  const float* W2 = (const float*)d_in[4];
  const float* b2 = (const float*)d_in[5];
  float* out = (float*)d_out;

  // workspace carve-up (int units). deg|fill|gcnt contiguous -> one memset.
  int*   ws_i   = (int*)d_ws;
  int*   deg    = ws_i + 0;                 // 100000
  int*   fill   = ws_i + 100000;            // 100000
  int*   gcnt   = ws_i + 200000;            // 1
  int*   rowptr = ws_i + 200004;            // 100000
  float* dis    = (float*)(ws_i + 300004);  // 100000
  uint*  es     = (uint*)(ws_i + 400004);   // 1700000
  uint*  H      = (uint*)(ws_i + 2100004);  // 6400000 (bf16x2; byte off 8400016, 16B-aligned)

  hipMemsetAsync(deg, 0, (size_t)200001*sizeof(int), stream);   // deg+fill+gcnt

  k_count  <<<6250,256, 0, stream>>>(ei + NE, deg);
  k_scan   <<<391, 256, 0, stream>>>(deg, rowptr, gcnt, dis);
  k_scatter<<<6641,256, 0, stream>>>(ei, dis, rowptr, fill, es);

  // layer 1: H = bf16(x@W1) ; out = elu(agg(H) + b1)   (d_out doubles as activation buffer)
  k_gemm<<<782,   256, 0, stream>>>(x, W1, H, NN);
  k_agg <<<25000, 256, 0, stream>>>(H, rowptr, deg, es, b1, out);
  // layer 2: H = bf16(out@W2) ; out = elu(agg(H) + b2)
  k_gemm<<<782,   256, 0, stream>>>(out, W2, H, NN);
  k_agg <<<25000, 256, 0, stream>>>(H, rowptr, deg, es, b2, out);
}

// Round 4
// 432.137 us; speedup vs baseline: 1.5112x; 1.0136x over previous
//
#include <hip/hip_runtime.h>
#include <math.h>

#define NN 100000
#define NE 1600000
#define NT (NE + NN)   // 1700000 edges incl. self-loops
#define DD 128

typedef unsigned int uint;

// round-to-nearest-even fp32 -> bf16 (16-bit payload in a uint)
__device__ __forceinline__ uint bfr(float f){
  uint u = __float_as_uint(f);
  return (u + 0x7FFFu + ((u >> 16) & 1u)) >> 16;
}
__device__ __forceinline__ uint pk2(float a, float b){
  return (bfr(a) & 0xFFFFu) | (bfr(b) << 16);
}

// ---------------- preprocessing ----------------

// deg[] zeroed by memset; counts in-edges only (self-loop folded in as +1 later)
__global__ __launch_bounds__(256) void k_count(const int* __restrict__ dst, int* __restrict__ deg){
  int i = blockIdx.x*256 + threadIdx.x;
  if (i < NE) atomicAdd(&deg[dst[i]], 1);
}

// fused exclusive scan (block scan + global atomic base) + dis = rsqrt(deg+1)
// NOTE: rowptr ranges are disjoint+correct but NOT monotone across blocks
// (atomic base ordering) -> agg must use deg[] for the range end, not rowptr[n+1].
__global__ __launch_bounds__(256) void k_scan(const int* __restrict__ deg, int* __restrict__ rowptr,
                                              int* __restrict__ gcnt, float* __restrict__ dis){
  __shared__ int s[256];
  __shared__ int base;
  int t = threadIdx.x, i = blockIdx.x*256 + t;
  int v = (i < NN) ? (deg[i] + 1) : 0;
  s[t] = v;
  __syncthreads();
  for (int off = 1; off < 256; off <<= 1){
    int a = (t >= off) ? s[t-off] : 0;
    __syncthreads();
    s[t] += a;
    __syncthreads();
  }
  if (t == 255) base = atomicAdd(gcnt, s[255]);
  __syncthreads();
  if (i < NN){
    rowptr[i] = base + s[t] - v;
    dis[i] = rsqrtf((float)(deg[i] + 1));
  }
}

// counting-sort edges by dst; descriptor = src(17b) | norm-bf16-sans-sign(15b)<<17
// (norm in (0,1] -> bf16 bit15 is 0, lossless in 15 bits)
__global__ __launch_bounds__(256) void k_scatter(const int* __restrict__ ei, const float* __restrict__ dis,
    const int* __restrict__ rowptr, int* __restrict__ fill, uint* __restrict__ es){
  int i = blockIdx.x*256 + threadIdx.x;
  if (i < NE){
    int s = ei[i];           // src row
    int d = ei[NE + i];      // dst row
    int p = rowptr[d] + atomicAdd(&fill[d], 1);
    es[p] = (uint)s | ((bfr(dis[s] * dis[d]) & 0x7FFFu) << 17);
  } else if (i < NT){
    int n = i - NE;          // self-loop
    int p = rowptr[n] + atomicAdd(&fill[n], 1);
    float dn = dis[n];
    es[p] = (uint)n | ((bfr(dn * dn) & 0x7FFFu) << 17);
  }
}

// ---------------- GEMM -> bf16: Y[nrows,128](bf16) = X[nrows,128] @ W[128,128] ----------------
// 128 rows/block, 256 threads, 8x8 register tile/thread, quarter-K phases.
// LDS: Ws 16KB + Xt 16KB = 32KB -> 3 blocks/CU (782 blocks ~ all resident, no tail wave).
// IN_BF16: X is packed bf16x2 (uint per channel pair) instead of fp32.
template<int IN_BF16>
__global__ __launch_bounds__(256, 3) void k_gemm(const void* __restrict__ Xv, const float* __restrict__ W,
    uint* __restrict__ Y, int nrows){
  __shared__ float Ws[32*128];   // [k_local][col]
  __shared__ float Xt[32*128];   // [k_local][row], XOR-swizzled rows
  int t = threadIdx.x;
  int row0 = blockIdx.x * 128;
  int tc = t & 15, tr = t >> 4;
  float acc[8][8];
  #pragma unroll
  for (int i=0;i<8;i++)
    #pragma unroll
    for (int j=0;j<8;j++) acc[i][j]=0.f;

  for (int ph = 0; ph < 4; ++ph){
    // stage W rows ph*32..+31 (linear, coalesced): 1024 float4
    #pragma unroll
    for (int it = 0; it < 4; ++it){
      int f = it*256 + t;
      ((float4*)Ws)[f] = ((const float4*)W)[ph*1024 + f];
    }
    // stage X rows row0..row0+127, k ph*32..+31, transposed + XOR swizzle
    if (!IN_BF16){
      const float* X = (const float*)Xv;
      #pragma unroll
      for (int it = 0; it < 4; ++it){
        int f = it*256 + t;                  // 0..1023
        int r  = f >> 3;                     // local row 0..127
        int c4 = f & 7;                      // float4 within k-quarter
        int gr = row0 + r;
        float4 v;
        if (gr < nrows) v = ((const float4*)X)[(size_t)gr*32 + ph*8 + c4];
        else            v = make_float4(0.f,0.f,0.f,0.f);
        int swz = (c4 & 3) << 3;             // ((k>>2)&3)<<3 for k=4*c4+j
        int rp  = r ^ swz;
        Xt[(c4*4+0)*128 + rp] = v.x;
        Xt[(c4*4+1)*128 + rp] = v.y;
        Xt[(c4*4+2)*128 + rp] = v.z;
        Xt[(c4*4+3)*128 + rp] = v.w;
      }
    } else {
      const uint* X = (const uint*)Xv;       // 64 uints (128 bf16) per row
      #pragma unroll
      for (int it = 0; it < 2; ++it){
        int f = it*256 + t;                  // 0..511
        int r  = f >> 2;                     // local row 0..127
        int c8 = f & 3;                      // uint4 (8 bf16) within k-quarter
        int gr = row0 + r;
        uint4 u;
        if (gr < nrows) u = ((const uint4*)X)[(size_t)gr*16 + ph*4 + c8];
        else            u = make_uint4(0,0,0,0);
        int kb = c8*8;
        int swzA = ((c8*2  ) & 3) << 3;      // k>>2 for first 4 of the 8
        int swzB = ((c8*2+1) & 3) << 3;      // k>>2 for last 4
        int rpA = r ^ swzA, rpB = r ^ swzB;
        Xt[(kb+0)*128 + rpA] = __uint_as_float(u.x << 16);
        Xt[(kb+1)*128 + rpA] = __uint_as_float(u.x & 0xFFFF0000u);
        Xt[(kb+2)*128 + rpA] = __uint_as_float(u.y << 16);
        Xt[(kb+3)*128 + rpA] = __uint_as_float(u.y & 0xFFFF0000u);
        Xt[(kb+4)*128 + rpB] = __uint_as_float(u.z << 16);
        Xt[(kb+5)*128 + rpB] = __uint_as_float(u.z & 0xFFFF0000u);
        Xt[(kb+6)*128 + rpB] = __uint_as_float(u.w << 16);
        Xt[(kb+7)*128 + rpB] = __uint_as_float(u.w & 0xFFFF0000u);
      }
    }
    __syncthreads();
    #pragma unroll 4
    for (int kl = 0; kl < 32; ++kl){
      int swz = ((kl >> 2) & 3) << 3;
      int xb  = kl*128 + ((tr*8) ^ swz);     // swz has no bit 2 -> +4 stays consistent
      float4 xa = *(const float4*)&Xt[xb];
      float4 xc = *(const float4*)&Xt[xb + 4];
      float4 wa = *(const float4*)&Ws[kl*128 + tc*8];
      float4 wb = *(const float4*)&Ws[kl*128 + tc*8 + 4];
      float xr[8] = {xa.x,xa.y,xa.z,xa.w,xc.x,xc.y,xc.z,xc.w};
      float wr[8] = {wa.x,wa.y,wa.z,wa.w,wb.x,wb.y,wb.z,wb.w};
      #pragma unroll
      for (int i=0;i<8;i++)
        #pragma unroll
        for (int j=0;j<8;j++)
          acc[i][j] = fmaf(xr[i], wr[j], acc[i][j]);
    }
    __syncthreads();
  }
  #pragma unroll
  for (int i=0;i<8;i++){
    int r = row0 + tr*8 + i;
    if (r < nrows){
      uint4 o;
      o.x = pk2(acc[i][0], acc[i][1]);
      o.y = pk2(acc[i][2], acc[i][3]);
      o.z = pk2(acc[i][4], acc[i][5]);
      o.w = pk2(acc[i][6], acc[i][7]);
      ((uint4*)Y)[(size_t)r*16 + tc] = o;    // 64 uints (128 bf16) per row
    }
  }
}

// ---------------- CSR aggregation + bias + ELU ----------------
// one WAVE per node (4 nodes / 256-thread block); lane = bf16 channel pair;
// 16x edge unroll (es loads coalesce to dwordx4) -> 16 gathers in flight.
// OUT_BF16: write packed bf16 (layer-1 activations) instead of fp32.
template<int OUT_BF16>
__global__ __launch_bounds__(256) void k_agg(const uint* __restrict__ H,
    const int* __restrict__ rowptr, const int* __restrict__ deg,
    const uint* __restrict__ es, const float* __restrict__ bias,
    void* __restrict__ outv){
  int wid  = threadIdx.x >> 6;
  int lane = threadIdx.x & 63;
  int n = blockIdx.x*4 + wid;            // grid*4 == NN exactly
  int e0 = rowptr[n];
  int e1 = e0 + deg[n] + 1;
  float a0 = 0.f, a1 = 0.f, a2 = 0.f, a3 = 0.f;
  int e = e0;

#define ASTEP(k,A,B) { uint p##k = es[e+k]; \
    uint h##k = H[(size_t)(p##k & 0x1FFFFu)*64 + lane]; \
    float w##k = __uint_as_float((p##k >> 17) << 16); \
    A = fmaf(w##k, __uint_as_float(h##k << 16), A); \
    B = fmaf(w##k, __uint_as_float(h##k & 0xFFFF0000u), B); }

  for (; e + 16 <= e1; e += 16){
    ASTEP( 0,a0,a1) ASTEP( 1,a2,a3) ASTEP( 2,a0,a1) ASTEP( 3,a2,a3)
    ASTEP( 4,a0,a1) ASTEP( 5,a2,a3) ASTEP( 6,a0,a1) ASTEP( 7,a2,a3)
    ASTEP( 8,a0,a1) ASTEP( 9,a2,a3) ASTEP(10,a0,a1) ASTEP(11,a2,a3)
    ASTEP(12,a0,a1) ASTEP(13,a2,a3) ASTEP(14,a0,a1) ASTEP(15,a2,a3)
  }
  for (; e + 4 <= e1; e += 4){
    ASTEP(0,a0,a1) ASTEP(1,a2,a3) ASTEP(2,a0,a1) ASTEP(3,a2,a3)
  }
  for (; e < e1; ++e){
    ASTEP(0,a0,a1)
  }
#undef ASTEP

  float2 b = *(const float2*)&bias[lane*2];
  float v0 = a0 + a2 + b.x, v1 = a1 + a3 + b.y;
  v0 = (v0 > 0.f) ? v0 : expm1f(v0);
  v1 = (v1 > 0.f) ? v1 : expm1f(v1);
  if (OUT_BF16){
    ((uint*)outv)[(size_t)n*64 + lane] = pk2(v0, v1);
  } else {
    float2 o; o.x = v0; o.y = v1;
    *(float2*)&((float*)outv)[(size_t)n*DD + lane*2] = o;
  }
}

// ---------------- launch ----------------

extern "C" void kernel_launch(void* const* d_in, const int* in_sizes, int n_in,
                              void* d_out, int out_size, void* d_ws, size_t ws_size,
                              hipStream_t stream){
  const float* x  = (const float*)d_in[0];
  const int*   ei = (const int*)d_in[1];   // [2, NE]: src row then dst row
  const float* W1 = (const float*)d_in[2];
  const float* b1 = (const float*)d_in[3];
  const float* W2 = (const float*)d_in[4];
  const float* b2 = (const float*)d_in[5];

  // workspace carve-up (int units). deg|fill|gcnt contiguous -> one memset.
  int*   ws_i   = (int*)d_ws;
  int*   deg    = ws_i + 0;                 // 100000
  int*   fill   = ws_i + 100000;            // 100000
  int*   gcnt   = ws_i + 200000;            // 1
  int*   rowptr = ws_i + 200004;            // 100000
  float* dis    = (float*)(ws_i + 300004);  // 100000
  uint*  es     = (uint*)(ws_i + 400004);   // 1700000
  uint*  H      = (uint*)(ws_i + 2100004);  // 6400000 (bf16x2; byte off 8400016, 16B-aligned)
  uint*  out1   = (uint*)(ws_i + 8500004);  // 3200000 (bf16x2; byte off 34000016, 16B-aligned)

  hipMemsetAsync(deg, 0, (size_t)200001*sizeof(int), stream);   // deg+fill+gcnt

  k_count  <<<6250,256, 0, stream>>>(ei + NE, deg);
  k_scan   <<<391, 256, 0, stream>>>(deg, rowptr, gcnt, dis);
  k_scatter<<<6641,256, 0, stream>>>(ei, dis, rowptr, fill, es);

  // layer 1: H = bf16(x@W1) ; out1 = bf16(elu(agg(H) + b1))
  k_gemm<0><<<782,   256, 0, stream>>>(x, W1, H, NN);
  k_agg<1> <<<25000, 256, 0, stream>>>(H, rowptr, deg, es, b1, out1);
  // layer 2: H = bf16(out1@W2) ; out = elu(agg(H) + b2)
  k_gemm<1><<<782,   256, 0, stream>>>(out1, W2, H, NN);
  k_agg<0> <<<25000, 256, 0, stream>>>(H, rowptr, deg, es, b2, d_out);
}

// Round 5
// 342.180 us; speedup vs baseline: 1.9085x; 1.2629x over previous
//
#include <hip/hip_runtime.h>
#include <math.h>

#define NN 100000
#define NE 1600000
#define NT (NE + NN)   // 1700000 edges incl. self-loops
#define DD 128
#define NB 500          // dst buckets
#define BR 200          // node range per bucket (NB*BR == NN)
#define BCAP 4096       // bucket capacity (mean 3200, sigma 56 -> 15.9 sigma headroom)
#define BMAGIC 21474837u // ceil(2^32/200); verified exact for d < 100000

typedef unsigned int uint;

// round-to-nearest-even fp32 -> bf16 (16-bit payload in a uint)
__device__ __forceinline__ uint bfr(float f){
  uint u = __float_as_uint(f);
  return (u + 0x7FFFu + ((u >> 16) & 1u)) >> 16;
}
__device__ __forceinline__ uint pk2(float a, float b){
  return (bfr(a) & 0xFFFFu) | (bfr(b) << 16);
}

// ---------------- preprocessing: LDS-local bucket sort ----------------

// pass 1: scatter edges into dst-range buckets; entry = src(17b) | d_local(8b)<<17
__global__ __launch_bounds__(256) void k_bucket(const int* __restrict__ ei,
    int* __restrict__ bcnt, uint* __restrict__ bedge){
  int i = blockIdx.x*256 + threadIdx.x;
  if (i < NE){
    uint s = (uint)ei[i];
    uint d = (uint)ei[NE + i];
    uint b = __umulhi(d, BMAGIC);          // d / 200
    uint dl = d - b*BR;
    int p = atomicAdd(&bcnt[b*16], 1);     // counters padded to 64B lines
    bedge[(size_t)b*BCAP + p] = s | (dl << 17);
  }
}

// pass 2: per-bucket LDS degree count -> coalesced deg/dis writes
__global__ __launch_bounds__(256) void k_deg(const int* __restrict__ bcnt,
    const uint* __restrict__ bedge, int* __restrict__ deg, float* __restrict__ dis){
  __shared__ int cl[BR];
  int b = blockIdx.x, t = threadIdx.x;
  if (t < BR) cl[t] = 0;
  __syncthreads();
  int cnt = bcnt[b*16];
  for (int e = t; e < cnt; e += 256){
    uint u = bedge[(size_t)b*BCAP + e];
    atomicAdd(&cl[u >> 17], 1);
  }
  __syncthreads();
  if (t < BR){
    int n = b*BR + t;
    int dg = cl[t];
    deg[n] = dg;                           // in-degree excl self-loop
    dis[n] = rsqrtf((float)(dg + 1));
  }
}

// pass 3: per-bucket CSR build: LDS count + scan, norms, contiguous es/rowptr writes
__global__ __launch_bounds__(256) void k_build(const int* __restrict__ bcnt,
    const uint* __restrict__ bedge, const float* __restrict__ dis,
    int* __restrict__ rowptr, uint* __restrict__ es){
  __shared__ uint  eL[BCAP];
  __shared__ int   cl[BR];
  __shared__ int   fl[BR];
  __shared__ float dl_[BR];
  __shared__ int   pf[256];
  __shared__ int   red[256];
  int b = blockIdx.x, t = threadIdx.x;

  // base = sum_{b'<b} bcnt[b'] + BR*b (self-loops)
  int part = 0;
  for (int i = t; i < b; i += 256) part += bcnt[i*16];
  red[t] = part;
  __syncthreads();
  for (int off = 128; off > 0; off >>= 1){
    if (t < off) red[t] += red[t + off];
    __syncthreads();
  }
  int base = red[0] + b*BR;

  if (t < BR){ cl[t] = 0; fl[t] = 0; }
  __syncthreads();
  int cnt = bcnt[b*16];
  for (int e = t; e < cnt; e += 256){
    uint u = bedge[(size_t)b*BCAP + e];
    eL[e] = u;
    atomicAdd(&cl[u >> 17], 1);
  }
  __syncthreads();
  // inclusive scan over (cl[i]+1)
  int v = (t < BR) ? (cl[t] + 1) : 0;
  pf[t] = v;
  __syncthreads();
  for (int off = 1; off < 256; off <<= 1){
    int a = (t >= off) ? pf[t-off] : 0;
    __syncthreads();
    pf[t] += a;
    __syncthreads();
  }
  if (t < BR){
    int n  = b*BR + t;
    int p0 = base + pf[t] - v;             // exclusive prefix
    rowptr[n] = p0;
    float dn = dis[n];
    dl_[t] = dn;
    es[p0 + cl[t]] = (uint)n | ((bfr(dn*dn) & 0x7FFFu) << 17);  // self-loop last
  }
  __syncthreads();
  for (int e = t; e < cnt; e += 256){
    uint u = eL[e];
    uint s = u & 0x1FFFFu;
    int  dloc = u >> 17;
    int  q  = atomicAdd(&fl[dloc], 1);
    int  p0 = base + pf[dloc] - (cl[dloc] + 1);
    es[p0 + q] = s | ((bfr(dis[s] * dl_[dloc]) & 0x7FFFu) << 17);
  }
}

// ---------------- GEMM -> bf16: Y[nrows,128](bf16) = X[nrows,128] @ W[128,128] ----------------
// 128 rows/block, 256 threads, 8x8 register tile/thread, quarter-K phases.
// LDS: Ws 16KB + Xt 16KB = 32KB -> 3 blocks/CU (782 blocks ~ all resident).
template<int IN_BF16>
__global__ __launch_bounds__(256, 3) void k_gemm(const void* __restrict__ Xv, const float* __restrict__ W,
    uint* __restrict__ Y, int nrows){
  __shared__ float Ws[32*128];   // [k_local][col]
  __shared__ float Xt[32*128];   // [k_local][row], XOR-swizzled rows
  int t = threadIdx.x;
  int row0 = blockIdx.x * 128;
  int tc = t & 15, tr = t >> 4;
  float acc[8][8];
  #pragma unroll
  for (int i=0;i<8;i++)
    #pragma unroll
    for (int j=0;j<8;j++) acc[i][j]=0.f;

  for (int ph = 0; ph < 4; ++ph){
    #pragma unroll
    for (int it = 0; it < 4; ++it){
      int f = it*256 + t;
      ((float4*)Ws)[f] = ((const float4*)W)[ph*1024 + f];
    }
    if (!IN_BF16){
      const float* X = (const float*)Xv;
      #pragma unroll
      for (int it = 0; it < 4; ++it){
        int f = it*256 + t;                  // 0..1023
        int r  = f >> 3;                     // local row 0..127
        int c4 = f & 7;                      // float4 within k-quarter
        int gr = row0 + r;
        float4 v;
        if (gr < nrows) v = ((const float4*)X)[(size_t)gr*32 + ph*8 + c4];
        else            v = make_float4(0.f,0.f,0.f,0.f);
        int swz = (c4 & 3) << 3;             // ((k>>2)&3)<<3 for k=4*c4+j
        int rp  = r ^ swz;
        Xt[(c4*4+0)*128 + rp] = v.x;
        Xt[(c4*4+1)*128 + rp] = v.y;
        Xt[(c4*4+2)*128 + rp] = v.z;
        Xt[(c4*4+3)*128 + rp] = v.w;
      }
    } else {
      const uint* X = (const uint*)Xv;       // 64 uints (128 bf16) per row
      #pragma unroll
      for (int it = 0; it < 2; ++it){
        int f = it*256 + t;                  // 0..511
        int r  = f >> 2;                     // local row 0..127
        int c8 = f & 3;                      // uint4 (8 bf16) within k-quarter
        int gr = row0 + r;
        uint4 u;
        if (gr < nrows) u = ((const uint4*)X)[(size_t)gr*16 + ph*4 + c8];
        else            u = make_uint4(0,0,0,0);
        int kb = c8*8;
        int swzA = ((c8*2  ) & 3) << 3;
        int swzB = ((c8*2+1) & 3) << 3;
        int rpA = r ^ swzA, rpB = r ^ swzB;
        Xt[(kb+0)*128 + rpA] = __uint_as_float(u.x << 16);
        Xt[(kb+1)*128 + rpA] = __uint_as_float(u.x & 0xFFFF0000u);
        Xt[(kb+2)*128 + rpA] = __uint_as_float(u.y << 16);
        Xt[(kb+3)*128 + rpA] = __uint_as_float(u.y & 0xFFFF0000u);
        Xt[(kb+4)*128 + rpB] = __uint_as_float(u.z << 16);
        Xt[(kb+5)*128 + rpB] = __uint_as_float(u.z & 0xFFFF0000u);
        Xt[(kb+6)*128 + rpB] = __uint_as_float(u.w << 16);
        Xt[(kb+7)*128 + rpB] = __uint_as_float(u.w & 0xFFFF0000u);
      }
    }
    __syncthreads();
    #pragma unroll 4
    for (int kl = 0; kl < 32; ++kl){
      int swz = ((kl >> 2) & 3) << 3;
      int xb  = kl*128 + ((tr*8) ^ swz);
      float4 xa = *(const float4*)&Xt[xb];
      float4 xc = *(const float4*)&Xt[xb + 4];
      float4 wa = *(const float4*)&Ws[kl*128 + tc*8];
      float4 wb = *(const float4*)&Ws[kl*128 + tc*8 + 4];
      float xr[8] = {xa.x,xa.y,xa.z,xa.w,xc.x,xc.y,xc.z,xc.w};
      float wr[8] = {wa.x,wa.y,wa.z,wa.w,wb.x,wb.y,wb.z,wb.w};
      #pragma unroll
      for (int i=0;i<8;i++)
        #pragma unroll
        for (int j=0;j<8;j++)
          acc[i][j] = fmaf(xr[i], wr[j], acc[i][j]);
    }
    __syncthreads();
  }
  #pragma unroll
  for (int i=0;i<8;i++){
    int r = row0 + tr*8 + i;
    if (r < nrows){
      uint4 o;
      o.x = pk2(acc[i][0], acc[i][1]);
      o.y = pk2(acc[i][2], acc[i][3]);
      o.z = pk2(acc[i][4], acc[i][5]);
      o.w = pk2(acc[i][6], acc[i][7]);
      ((uint4*)Y)[(size_t)r*16 + tc] = o;
    }
  }
}

// ---------------- CSR aggregation + bias + ELU ----------------
// one WAVE per node (4 nodes / 256-thread block); lane = bf16 channel pair;
// 16x edge unroll -> 16 gathers in flight per wave.
template<int OUT_BF16>
__global__ __launch_bounds__(256) void k_agg(const uint* __restrict__ H,
    const int* __restrict__ rowptr, const int* __restrict__ deg,
    const uint* __restrict__ es, const float* __restrict__ bias,
    void* __restrict__ outv){
  int wid  = threadIdx.x >> 6;
  int lane = threadIdx.x & 63;
  int n = blockIdx.x*4 + wid;            // grid*4 == NN exactly
  int e0 = rowptr[n];
  int e1 = e0 + deg[n] + 1;
  float a0 = 0.f, a1 = 0.f, a2 = 0.f, a3 = 0.f;
  int e = e0;

#define ASTEP(k,A,B) { uint p##k = es[e+k]; \
    uint h##k = H[(size_t)(p##k & 0x1FFFFu)*64 + lane]; \
    float w##k = __uint_as_float((p##k >> 17) << 16); \
    A = fmaf(w##k, __uint_as_float(h##k << 16), A); \
    B = fmaf(w##k, __uint_as_float(h##k & 0xFFFF0000u), B); }

  for (; e + 16 <= e1; e += 16){
    ASTEP( 0,a0,a1) ASTEP( 1,a2,a3) ASTEP( 2,a0,a1) ASTEP( 3,a2,a3)
    ASTEP( 4,a0,a1) ASTEP( 5,a2,a3) ASTEP( 6,a0,a1) ASTEP( 7,a2,a3)
    ASTEP( 8,a0,a1) ASTEP( 9,a2,a3) ASTEP(10,a0,a1) ASTEP(11,a2,a3)
    ASTEP(12,a0,a1) ASTEP(13,a2,a3) ASTEP(14,a0,a1) ASTEP(15,a2,a3)
  }
  for (; e + 4 <= e1; e += 4){
    ASTEP(0,a0,a1) ASTEP(1,a2,a3) ASTEP(2,a0,a1) ASTEP(3,a2,a3)
  }
  for (; e < e1; ++e){
    ASTEP(0,a0,a1)
  }
#undef ASTEP

  float2 b = *(const float2*)&bias[lane*2];
  float v0 = a0 + a2 + b.x, v1 = a1 + a3 + b.y;
  v0 = (v0 > 0.f) ? v0 : expm1f(v0);
  v1 = (v1 > 0.f) ? v1 : expm1f(v1);
  if (OUT_BF16){
    ((uint*)outv)[(size_t)n*64 + lane] = pk2(v0, v1);
  } else {
    float2 o; o.x = v0; o.y = v1;
    *(float2*)&((float*)outv)[(size_t)n*DD + lane*2] = o;
  }
}

// ---------------- launch ----------------

extern "C" void kernel_launch(void* const* d_in, const int* in_sizes, int n_in,
                              void* d_out, int out_size, void* d_ws, size_t ws_size,
                              hipStream_t stream){
  const float* x  = (const float*)d_in[0];
  const int*   ei = (const int*)d_in[1];   // [2, NE]: src row then dst row
  const float* W1 = (const float*)d_in[2];
  const float* b1 = (const float*)d_in[3];
  const float* W2 = (const float*)d_in[4];
  const float* b2 = (const float*)d_in[5];

  // workspace carve-up (int units), total 46.43 MB (proven <= ws_size in R4):
  //   bedge (8.2MB, dead after k_build) aliases H (written first by k_gemm<0>)
  int*   ws_i   = (int*)d_ws;
  int*   bcnt   = ws_i + 0;                 // 500*16 = 8000 (64B-padded counters)
  int*   deg    = ws_i + 8000;              // 100000
  float* dis    = (float*)(ws_i + 108000);  // 100000
  int*   rowptr = ws_i + 208000;            // 100000
  uint*  es     = (uint*)(ws_i + 308000);   // 1700000
  uint*  H      = (uint*)(ws_i + 2008000);  // 6400000 bf16x2 (byte 8032000, 16B-aligned)
  uint*  bedge  = H;                        // alias: 500*4096 = 2048000 uints
  uint*  out1   = (uint*)(ws_i + 8408000);  // 3200000 bf16x2

  hipMemsetAsync(bcnt, 0, 8000*sizeof(int), stream);

  k_bucket<<<6250, 256, 0, stream>>>(ei, bcnt, bedge);
  k_deg   <<<NB,   256, 0, stream>>>(bcnt, bedge, deg, dis);
  k_build <<<NB,   256, 0, stream>>>(bcnt, bedge, dis, rowptr, es);

  // layer 1: H = bf16(x@W1) ; out1 = bf16(elu(agg(H) + b1))
  k_gemm<0><<<782,   256, 0, stream>>>(x, W1, H, NN);
  k_agg<1> <<<25000, 256, 0, stream>>>(H, rowptr, deg, es, b1, out1);
  // layer 2: H = bf16(out1@W2) ; out = elu(agg(H) + b2)
  k_gemm<1><<<782,   256, 0, stream>>>(out1, W2, H, NN);
  k_agg<0> <<<25000, 256, 0, stream>>>(H, rowptr, deg, es, b2, d_out);
}